// Round 1
// baseline (181764.331 us; speedup 1.0000x reference)
//
#include <hip/hip_runtime.h>
#include <math.h>

#define T_DIM 128
#define B_DIM 256
#define X_DIMC 256
#define H_DIMC 1024
#define Z_DIMC 128
#define TBROWS (T_DIM * B_DIM)
#define EPSF 1.1920929e-07f
#define HALF_LOG_2PI 0.91893853320467274f

__device__ __forceinline__ float act_apply(float x, int act) {
    if (act == 1) return fmaxf(x, 0.f);
    if (act == 2) return x > 0.f ? x + log1pf(expf(-x)) : log1pf(expf(x));
    return x;
}

// Generic fp32 GEMM: C = act(A @ B + bias)
//  - A is a virtual [M,K] row-major matrix: col k < ksplit comes from A0 (lda0),
//    otherwise from A1 (lda1) at col k-ksplit  (fuses concat([A0,A1], axis=1)).
//  - ZMODE=1: A(m,k) = A0(m,k) + Aeps(m,k)*A1(m,k)   (fuses z = mean + eps*std).
//  - B is a virtual [K,N] row-major matrix: col n < nsplit from B0, else B1.
//  - Output col n < nsplit -> out0 with bias0/act0; else out1 (col n-nsplit)
//    with bias1/act1. (fuses the mean/std head pairs; single-B GEMMs pass
//    nsplit >= N and duplicate pointers.)
template <int BM, int BN, int BK, int TM, int TN, int ZMODE>
__global__ __launch_bounds__((BM / TM) * (BN / TN)) void gemm_k(
    const float* __restrict__ A0, int lda0,
    const float* __restrict__ A1, int lda1, int ksplit,
    const float* __restrict__ Aeps,
    const float* __restrict__ B0, int ldb0,
    const float* __restrict__ B1, int ldb1, int nsplit,
    const float* __restrict__ bias0, const float* __restrict__ bias1,
    float* __restrict__ out0, int ldo0, int act0,
    float* __restrict__ out1, int ldo1, int act1,
    int K)
{
    constexpr int NT = (BM / TM) * (BN / TN);
    __shared__ float As[BK][BM + 1];
    __shared__ float Bs[BK][BN + 1];
    const int tid = threadIdx.x;
    const int bm0 = blockIdx.x * BM;
    const int bn0 = blockIdx.y * BN;
    constexpr int TCOLS = BN / TN;
    const int m0 = (tid / TCOLS) * TM;
    const int n0 = (tid % TCOLS) * TN;
    float acc[TM][TN] = {};

    for (int k0 = 0; k0 < K; k0 += BK) {
#pragma unroll
        for (int i = tid; i < BM * BK; i += NT) {
            const int m = i / BK, k = i % BK;
            const int gm = bm0 + m, gk = k0 + k;
            float v;
            if (ZMODE) {
                v = fmaf(Aeps[(size_t)gm * lda0 + gk], A1[(size_t)gm * lda0 + gk],
                         A0[(size_t)gm * lda0 + gk]);
            } else {
                v = (gk < ksplit) ? A0[(size_t)gm * lda0 + gk]
                                  : A1[(size_t)gm * lda1 + (gk - ksplit)];
            }
            As[k][m] = v;
        }
#pragma unroll
        for (int i = tid; i < BK * BN; i += NT) {
            const int k = i / BN, n = i % BN;
            const int gn = bn0 + n, gk = k0 + k;
            Bs[k][n] = (gn < nsplit) ? B0[(size_t)gk * ldb0 + gn]
                                     : B1[(size_t)gk * ldb1 + (gn - nsplit)];
        }
        __syncthreads();
#pragma unroll
        for (int k = 0; k < BK; ++k) {
            float a[TM], b[TN];
#pragma unroll
            for (int i = 0; i < TM; ++i) a[i] = As[k][m0 + i];
#pragma unroll
            for (int j = 0; j < TN; ++j) b[j] = Bs[k][n0 + j];
#pragma unroll
            for (int i = 0; i < TM; ++i)
#pragma unroll
                for (int j = 0; j < TN; ++j)
                    acc[i][j] = fmaf(a[i], b[j], acc[i][j]);
        }
        __syncthreads();
    }

#pragma unroll
    for (int i = 0; i < TM; ++i) {
        const int gm = bm0 + m0 + i;
#pragma unroll
        for (int j = 0; j < TN; ++j) {
            const int gn = bn0 + n0 + j;
            if (gn < nsplit) {
                float v = acc[i][j] + bias0[gn];
                out0[(size_t)gm * ldo0 + gn] = act_apply(v, act0);
            } else {
                float v = acc[i][j] + bias1[gn - nsplit];
                out1[(size_t)gm * ldo1 + (gn - nsplit)] = act_apply(v, act1);
            }
        }
    }
}

// in[rows][cols] -> outp[cols][rows], 32x32 LDS tiles
__global__ void transpose_k(const float* __restrict__ in, float* __restrict__ outp,
                            int rows, int cols)
{
    __shared__ float tile[32][33];
    const int c0 = blockIdx.x * 32, r0 = blockIdx.y * 32;
    const int tx = threadIdx.x, ty = threadIdx.y;  // (32, 8)
    for (int i = ty; i < 32; i += 8)
        tile[i][tx] = in[(size_t)(r0 + i) * cols + (c0 + tx)];
    __syncthreads();
    for (int i = ty; i < 32; i += 8)
        outp[(size_t)(c0 + i) * rows + (r0 + tx)] = tile[tx][i];
}

__global__ void copy_k(const float* __restrict__ src, float* __restrict__ dst, int n)
{
    int i = blockIdx.x * blockDim.x + threadIdx.x;
    if (i < n) dst[i] = src[i];
}

__global__ void zero2_k(float* p)
{
    if (threadIdx.x < 2) p[threadIdx.x] = 0.f;
}

// h' = (1-u)*n + u*h  (pytorch GRU cell, gates precomputed with biases)
__global__ void gru_k(const float* __restrict__ gi, const float* __restrict__ gh,
                      const float* __restrict__ h, float* __restrict__ hn)
{
    int i = blockIdx.x * blockDim.x + threadIdx.x;
    if (i >= B_DIM * H_DIMC) return;
    const int b = i >> 10, j = i & (H_DIMC - 1);
    const float* gib = gi + (size_t)b * 3 * H_DIMC;
    const float* ghb = gh + (size_t)b * 3 * H_DIMC;
    const float r = 1.f / (1.f + expf(-(gib[j] + ghb[j])));
    const float u = 1.f / (1.f + expf(-(gib[H_DIMC + j] + ghb[H_DIMC + j])));
    const float n = tanhf(gib[2 * H_DIMC + j] + r * ghb[2 * H_DIMC + j]);
    hn[i] = (1.f - u) * n + u * h[i];
}

// blocks [0,128): kld over B*Z elems; blocks [128,384): nll over B*X elems
__global__ void loss_k(const float* __restrict__ em, const float* __restrict__ es,
                       const float* __restrict__ pm, const float* __restrict__ ps,
                       const float* __restrict__ xt, const float* __restrict__ dm,
                       const float* __restrict__ ds, float* __restrict__ outp)
{
    const int KB = (B_DIM * Z_DIMC) / 256;  // 128
    const int bid = blockIdx.x, tid = threadIdx.x;
    float v;
    int target;
    if (bid < KB) {
        const int i = bid * 256 + tid;
        const float dmn = em[i] - pm[i];
        v = 0.5f * (2.f * logf(ps[i] + EPSF) - 2.f * logf(es[i] + EPSF) +
                    (es[i] * es[i] + dmn * dmn) / (ps[i] * ps[i]) - 1.f);
        target = 0;
    } else {
        const int i = (bid - KB) * 256 + tid;
        const float d = ds[i];
        const float diff = xt[i] - dm[i];
        v = logf(d + EPSF) + HALF_LOG_2PI + diff * diff / (2.f * d * d);
        target = 1;
    }
    for (int o = 32; o > 0; o >>= 1) v += __shfl_down(v, o);
    __shared__ float sred[4];
    if ((tid & 63) == 0) sred[tid >> 6] = v;
    __syncthreads();
    if (tid == 0) atomicAdd(outp + target, sred[0] + sred[1] + sred[2] + sred[3]);
}

extern "C" void kernel_launch(void* const* d_in, const int* in_sizes, int n_in,
                              void* d_out_v, int out_size, void* d_ws, size_t ws_size,
                              hipStream_t stream)
{
    (void)in_sizes; (void)n_in; (void)out_size;
    const float* x    = (const float*)d_in[0];
    const float* h0   = (const float*)d_in[1];
    const float* eps  = (const float*)d_in[2];
    const float* Wpx  = (const float*)d_in[3];
    const float* bpx  = (const float*)d_in[4];
    const float* Wpz  = (const float*)d_in[5];
    const float* bpz  = (const float*)d_in[6];
    const float* Wenc = (const float*)d_in[7];
    const float* benc = (const float*)d_in[8];
    const float* Wem  = (const float*)d_in[9];
    const float* bem  = (const float*)d_in[10];
    const float* Wes  = (const float*)d_in[11];
    const float* bes  = (const float*)d_in[12];
    const float* Wpr  = (const float*)d_in[13];
    const float* bpr  = (const float*)d_in[14];
    const float* Wpm  = (const float*)d_in[15];
    const float* bpm  = (const float*)d_in[16];
    const float* Wps  = (const float*)d_in[17];
    const float* bps  = (const float*)d_in[18];
    const float* Wdec = (const float*)d_in[19];
    const float* bdec = (const float*)d_in[20];
    const float* Wdm  = (const float*)d_in[21];
    const float* bdm  = (const float*)d_in[22];
    const float* Wds  = (const float*)d_in[23];
    const float* bds  = (const float*)d_in[24];
    const float* W_ih = (const float*)d_in[25];
    const float* W_hh = (const float*)d_in[26];
    const float* b_ih = (const float*)d_in[27];
    const float* b_hh = (const float*)d_in[28];

    float* out = (float*)d_out_v;
    float* kld_nll  = out;
    float* enc_means = out + 2;
    float* enc_stds  = enc_means + (size_t)T_DIM * B_DIM * Z_DIMC;
    float* dec_means = enc_stds  + (size_t)T_DIM * B_DIM * Z_DIMC;
    float* dec_stds  = dec_means + (size_t)T_DIM * B_DIM * X_DIMC;

    float* ws = (float*)d_ws;
    size_t off = 0;
    auto take = [&](size_t n) { float* p = ws + off; off += n; return p; };
    float* WihT  = take((size_t)2 * H_DIMC * 3 * H_DIMC);  // [2048][3072]
    float* WhhT  = take((size_t)H_DIMC * 3 * H_DIMC);      // [1024][3072]
    float* hbuf0 = take((size_t)B_DIM * H_DIMC);
    float* hbuf1 = take((size_t)B_DIM * H_DIMC);
    float* enc   = take((size_t)B_DIM * H_DIMC);
    float* prior = take((size_t)B_DIM * H_DIMC);
    float* pmb   = take((size_t)B_DIM * Z_DIMC);
    float* psb   = take((size_t)B_DIM * Z_DIMC);
    float* phi_z = take((size_t)B_DIM * H_DIMC);
    float* decb  = take((size_t)B_DIM * H_DIMC);
    float* gib   = take((size_t)B_DIM * 3 * H_DIMC);
    float* ghb   = take((size_t)B_DIM * 3 * H_DIMC);
    const size_t base_floats = off;
    const size_t phiX_need = (size_t)TBROWS * H_DIMC;
    const bool big = (ws_size / sizeof(float)) >= base_floats + phiX_need;
    float* phiX = big ? take(phiX_need) : take((size_t)B_DIM * H_DIMC);

    const int BIG = 1 << 30;

    // one-time per call: transposed GRU weights, h init, loss accumulator zero
    transpose_k<<<dim3((2 * H_DIMC) / 32, (3 * H_DIMC) / 32), dim3(32, 8), 0, stream>>>(
        W_ih, WihT, 3 * H_DIMC, 2 * H_DIMC);
    transpose_k<<<dim3(H_DIMC / 32, (3 * H_DIMC) / 32), dim3(32, 8), 0, stream>>>(
        W_hh, WhhT, 3 * H_DIMC, H_DIMC);
    copy_k<<<(B_DIM * H_DIMC + 255) / 256, 256, 0, stream>>>(h0, hbuf0, B_DIM * H_DIMC);
    zero2_k<<<1, 64, 0, stream>>>(kld_nll);

    if (big) {
        // phi_x for all timesteps: [T*B,256] @ [256,1024]
        gemm_k<64, 64, 16, 4, 4, 0><<<dim3(TBROWS / 64, H_DIMC / 64), 256, 0, stream>>>(
            x, X_DIMC, x, X_DIMC, BIG, nullptr,
            Wpx, H_DIMC, Wpx, H_DIMC, BIG, bpx, bpx,
            phiX, H_DIMC, 1, phiX, H_DIMC, 1, X_DIMC);
    }

    for (int t = 0; t < T_DIM; ++t) {
        const float* hcur = (t & 1) ? hbuf1 : hbuf0;
        float* hnext      = (t & 1) ? hbuf0 : hbuf1;
        const float* phiXt = big ? (phiX + (size_t)t * B_DIM * H_DIMC) : phiX;
        float* em_t = enc_means + (size_t)t * B_DIM * Z_DIMC;
        float* es_t = enc_stds  + (size_t)t * B_DIM * Z_DIMC;
        float* dm_t = dec_means + (size_t)t * B_DIM * X_DIMC;
        float* ds_t = dec_stds  + (size_t)t * B_DIM * X_DIMC;
        const float* eps_t = eps + (size_t)t * B_DIM * Z_DIMC;
        const float* x_t   = x   + (size_t)t * B_DIM * X_DIMC;

        if (!big) {
            gemm_k<32, 64, 16, 2, 4, 0><<<dim3(8, 16), 256, 0, stream>>>(
                x_t, X_DIMC, x_t, X_DIMC, BIG, nullptr,
                Wpx, H_DIMC, Wpx, H_DIMC, BIG, bpx, bpx,
                phiX, H_DIMC, 1, phiX, H_DIMC, 1, X_DIMC);
        }
        // enc = relu([phi_x, h] @ Wenc + benc)
        gemm_k<32, 64, 16, 2, 4, 0><<<dim3(8, 16), 256, 0, stream>>>(
            phiXt, H_DIMC, hcur, H_DIMC, H_DIMC, nullptr,
            Wenc, H_DIMC, Wenc, H_DIMC, BIG, benc, benc,
            enc, H_DIMC, 1, enc, H_DIMC, 1, 2 * H_DIMC);
        // enc_mean -> d_out, enc_std = softplus -> d_out
        gemm_k<32, 32, 16, 2, 2, 0><<<dim3(8, 8), 256, 0, stream>>>(
            enc, H_DIMC, enc, H_DIMC, BIG, nullptr,
            Wem, Z_DIMC, Wes, Z_DIMC, Z_DIMC, bem, bes,
            em_t, Z_DIMC, 0, es_t, Z_DIMC, 2, H_DIMC);
        // phi_z = relu((em + eps*es) @ Wpz + bpz)   (z fused into A-load)
        gemm_k<32, 64, 16, 2, 4, 1><<<dim3(8, 16), 256, 0, stream>>>(
            em_t, Z_DIMC, es_t, Z_DIMC, BIG, eps_t,
            Wpz, H_DIMC, Wpz, H_DIMC, BIG, bpz, bpz,
            phi_z, H_DIMC, 1, phi_z, H_DIMC, 1, Z_DIMC);
        // prior = relu(h @ Wpr + bpr)
        gemm_k<32, 64, 16, 2, 4, 0><<<dim3(8, 16), 256, 0, stream>>>(
            hcur, H_DIMC, hcur, H_DIMC, BIG, nullptr,
            Wpr, H_DIMC, Wpr, H_DIMC, BIG, bpr, bpr,
            prior, H_DIMC, 1, prior, H_DIMC, 1, H_DIMC);
        // prior_mean, prior_std (ws only, feed kld)
        gemm_k<32, 32, 16, 2, 2, 0><<<dim3(8, 8), 256, 0, stream>>>(
            prior, H_DIMC, prior, H_DIMC, BIG, nullptr,
            Wpm, Z_DIMC, Wps, Z_DIMC, Z_DIMC, bpm, bps,
            pmb, Z_DIMC, 0, psb, Z_DIMC, 2, H_DIMC);
        // dec = relu([phi_z, h] @ Wdec + bdec)
        gemm_k<32, 64, 16, 2, 4, 0><<<dim3(8, 16), 256, 0, stream>>>(
            phi_z, H_DIMC, hcur, H_DIMC, H_DIMC, nullptr,
            Wdec, H_DIMC, Wdec, H_DIMC, BIG, bdec, bdec,
            decb, H_DIMC, 1, decb, H_DIMC, 1, 2 * H_DIMC);
        // dec_mean -> d_out, dec_std = softplus -> d_out
        gemm_k<32, 32, 16, 2, 2, 0><<<dim3(8, 16), 256, 0, stream>>>(
            decb, H_DIMC, decb, H_DIMC, BIG, nullptr,
            Wdm, X_DIMC, Wds, X_DIMC, X_DIMC, bdm, bds,
            dm_t, X_DIMC, 0, ds_t, X_DIMC, 2, H_DIMC);
        // gi = [phi_x, phi_z] @ W_ih^T + b_ih
        gemm_k<32, 64, 16, 2, 4, 0><<<dim3(8, 48), 256, 0, stream>>>(
            phiXt, H_DIMC, phi_z, H_DIMC, H_DIMC, nullptr,
            WihT, 3 * H_DIMC, WihT, 3 * H_DIMC, BIG, b_ih, b_ih,
            gib, 3 * H_DIMC, 0, gib, 3 * H_DIMC, 0, 2 * H_DIMC);
        // gh = h @ W_hh^T + b_hh
        gemm_k<32, 64, 16, 2, 4, 0><<<dim3(8, 48), 256, 0, stream>>>(
            hcur, H_DIMC, hcur, H_DIMC, BIG, nullptr,
            WhhT, 3 * H_DIMC, WhhT, 3 * H_DIMC, BIG, b_hh, b_hh,
            ghb, 3 * H_DIMC, 0, ghb, 3 * H_DIMC, 0, H_DIMC);
        // GRU combine
        gru_k<<<dim3((B_DIM * H_DIMC) / 256), 256, 0, stream>>>(gib, ghb, hcur, hnext);
        // kld/nll partial sums -> d_out[0], d_out[1]
        loss_k<<<dim3(384), 256, 0, stream>>>(em_t, es_t, pmb, psb, x_t, dm_t, ds_t, kld_nll);
    }
}

// Round 2
// 32319.580 us; speedup vs baseline: 5.6240x; 5.6240x over previous
//
#include <hip/hip_runtime.h>
#include <math.h>
#include <limits.h>

#define T_DIM 128
#define B_DIM 256
#define X_DIMC 256
#define H_DIMC 1024
#define Z_DIMC 128
#define EPSF 1.1920929e-07f
#define HALF_LOG_2PI 0.91893853320467274f

typedef float f32x4 __attribute__((ext_vector_type(4)));
typedef short bf16x8 __attribute__((ext_vector_type(8)));

struct Seg { int n_end; const float* bias; int act; float* of32; int ld32; short* ob16; int ld16; };
struct Segs { Seg s[4]; };

__device__ __forceinline__ short f2bf(float f) {
    unsigned u = __builtin_bit_cast(unsigned, f);
    u += 0x7fffu + ((u >> 16) & 1u);
    return (short)(u >> 16);
}
__device__ __forceinline__ float act_apply(float x, int act) {
    if (act == 1) return fmaxf(x, 0.f);
    if (act == 2) return x > 0.f ? x + log1pf(expf(-x)) : log1pf(expf(x));
    return x;
}

// bf16 MFMA GEMM. A: virtual [M,K] bf16, 3 k-segments (A0/A1/A2 at ks1/ks2)
// or ZM=1: A(m,k) = zm + ze*zs (fp32 reads, fuses reparam z). B: BT [N][K] bf16
// (pre-transposed weights). Output: up to 4 column segments, each with own
// bias, activation (0=none,1=relu,2=softplus), fp32 and/or bf16 destination.
template <int BM, int BN, int ZM>
__global__ __launch_bounds__(256) void mm_k(
    const short* __restrict__ A0, int lda0,
    const short* __restrict__ A1, int lda1,
    const short* __restrict__ A2, int lda2,
    int ks1, int ks2,
    const float* __restrict__ zm, const float* __restrict__ zs,
    const float* __restrict__ ze, int ldz,
    const short* __restrict__ BT, int ldb,
    Segs segs, int K)
{
    constexpr int BK = 32, PAD = 8, LDR = BK + PAD;
    constexpr int WM = BM / 2, WN = BN / 2, FM = WM / 16, FN = WN / 16;
    __shared__ short As[BM][LDR];
    __shared__ short Bs[BN][LDR];
    const int tid = threadIdx.x;
    const int lane = tid & 63, wid = tid >> 6;
    const int wm = (wid >> 1) * WM, wn = (wid & 1) * WN;
    const int bm0 = blockIdx.x * BM, bn0 = blockIdx.y * BN;
    const int l15 = lane & 15, lg = lane >> 4;
    f32x4 acc[FM][FN] = {};

    for (int k0 = 0; k0 < K; k0 += BK) {
        // stage A tile [BM][BK]
#pragma unroll
        for (int c = tid; c < BM * BK / 8; c += 256) {
            const int r = c >> 2, p = c & 3;  // BK/8 == 4 chunks per row
            const int gm = bm0 + r, gk = k0 + p * 8;
            bf16x8 v;
            if (ZM) {
                const size_t base = (size_t)gm * ldz + gk;
                float tmp[8];
#pragma unroll
                for (int q = 0; q < 8; q += 2) {
                    float2 m2 = *(const float2*)(zm + base + q);
                    float2 s2 = *(const float2*)(zs + base + q);
                    float2 e2 = *(const float2*)(ze + base + q);
                    tmp[q]     = fmaf(e2.x, s2.x, m2.x);
                    tmp[q + 1] = fmaf(e2.y, s2.y, m2.y);
                }
#pragma unroll
                for (int q = 0; q < 8; ++q) v[q] = f2bf(tmp[q]);
            } else {
                const short* Ap; int kk;
                if (gk < ks1)      { Ap = A0 + (size_t)gm * lda0; kk = gk; }
                else if (gk < ks2) { Ap = A1 + (size_t)gm * lda1; kk = gk - ks1; }
                else               { Ap = A2 + (size_t)gm * lda2; kk = gk - ks2; }
                v = *(const bf16x8*)(Ap + kk);
            }
            *(bf16x8*)(&As[r][p * 8]) = v;
        }
        // stage B tile [BN][BK] from BT[N][K]
#pragma unroll
        for (int c = tid; c < BN * BK / 8; c += 256) {
            const int r = c >> 2, p = c & 3;
            *(bf16x8*)(&Bs[r][p * 8]) =
                *(const bf16x8*)(BT + (size_t)(bn0 + r) * ldb + k0 + p * 8);
        }
        __syncthreads();
        bf16x8 af[FM], bfv[FN];
#pragma unroll
        for (int i = 0; i < FM; ++i)
            af[i] = *(const bf16x8*)(&As[wm + i * 16 + l15][lg * 8]);
#pragma unroll
        for (int j = 0; j < FN; ++j)
            bfv[j] = *(const bf16x8*)(&Bs[wn + j * 16 + l15][lg * 8]);
#pragma unroll
        for (int i = 0; i < FM; ++i)
#pragma unroll
            for (int j = 0; j < FN; ++j)
                acc[i][j] = __builtin_amdgcn_mfma_f32_16x16x32_bf16(
                    af[i], bfv[j], acc[i][j], 0, 0, 0);
        __syncthreads();
    }
    // epilogue: C/D frag mapping col=lane&15, row=(lane>>4)*4+r
#pragma unroll
    for (int j = 0; j < FN; ++j) {
        const int gn = bn0 + wn + j * 16 + l15;
        int q = 0, n0 = 0;
        while (gn >= segs.s[q].n_end) { n0 = segs.s[q].n_end; ++q; }
        const Seg sg = segs.s[q];
        const float bsv = sg.bias[gn - n0];
#pragma unroll
        for (int i = 0; i < FM; ++i) {
            const int gm0 = bm0 + wm + i * 16 + lg * 4;
#pragma unroll
            for (int r = 0; r < 4; ++r) {
                float v = act_apply(acc[i][j][r] + bsv, sg.act);
                if (sg.of32) sg.of32[(size_t)(gm0 + r) * sg.ld32 + (gn - n0)] = v;
                if (sg.ob16) sg.ob16[(size_t)(gm0 + r) * sg.ld16 + (gn - n0)] = f2bf(v);
            }
        }
    }
}

// dst[n0+n][k0+k] (bf16, ld ldd) = src[k][n]  (fp32, ld ldsr), LDS transpose
__global__ void packT_k(const float* __restrict__ src, int ldsr,
                        short* __restrict__ dst, int ldd, int n0, int k0)
{
    __shared__ float tile[32][33];
    const int bx = blockIdx.x * 32;  // n
    const int by = blockIdx.y * 32;  // k
    const int tx = threadIdx.x, ty = threadIdx.y;  // (32,8)
    for (int i = ty; i < 32; i += 8)
        tile[i][tx] = src[(size_t)(by + i) * ldsr + bx + tx];
    __syncthreads();
    for (int i = ty; i < 32; i += 8)
        dst[(size_t)(n0 + bx + i) * ldd + k0 + by + tx] = f2bf(tile[tx][i]);
}

// dst[n0+n][k0+k] = src[n][k] (no transpose; for W_ih/W_hh which are [N][K])
__global__ void packD_k(const float* __restrict__ src, int ldsr,
                        short* __restrict__ dst, int ldd, int n0, int k0, int kr)
{
    const int idx = blockIdx.x * 256 + threadIdx.x;
    const int n = idx / kr, k = idx % kr;
    dst[(size_t)(n0 + n) * ldd + k0 + k] = f2bf(src[(size_t)n * ldsr + k]);
}

__global__ void packZ_k(short* __restrict__ dst, int ldd, int n0, int k0, int kr)
{
    const int idx = blockIdx.x * 256 + threadIdx.x;
    const int n = idx / kr, k = idx % kr;
    dst[(size_t)(n0 + n) * ldd + k0 + k] = 0;
}

__global__ void cvtx_k(const float* __restrict__ x, short* __restrict__ xb)
{
    const int i = blockIdx.x * 256 + threadIdx.x;  // over n/4
    float4 v = ((const float4*)x)[i];
    short4 s;
    s.x = f2bf(v.x); s.y = f2bf(v.y); s.z = f2bf(v.z); s.w = f2bf(v.w);
    ((short4*)xb)[i] = s;
}

__global__ void hinit_k(const float* __restrict__ h0, float* __restrict__ hf,
                        short* __restrict__ hb)
{
    const int i = blockIdx.x * 256 + threadIdx.x;
    const float v = h0[i];
    hf[i] = v; hb[i] = f2bf(v);
}

__global__ void zero2_k(float* p) { if (threadIdx.x < 2) p[threadIdx.x] = 0.f; }

// blocks [0,1024): GRU combine; [1024,1152): kld; [1152,1408): nll
__global__ void tail_k(const float* __restrict__ gi, const float* __restrict__ gh,
                       const float* __restrict__ h, float* __restrict__ hn,
                       short* __restrict__ hnb,
                       const float* __restrict__ em, const float* __restrict__ es,
                       const float* __restrict__ pm, const float* __restrict__ ps,
                       const float* __restrict__ xt, const float* __restrict__ dm,
                       const float* __restrict__ ds, float* __restrict__ outp)
{
    int bid = blockIdx.x;
    const int tid = threadIdx.x;
    if (bid < (B_DIM * H_DIMC) / 256) {
        const int i = bid * 256 + tid;
        const int b = i >> 10, j = i & (H_DIMC - 1);
        const float* gib = gi + (size_t)b * 3 * H_DIMC;
        const float* ghb = gh + (size_t)b * 3 * H_DIMC;
        const float r = 1.f / (1.f + expf(-(gib[j] + ghb[j])));
        const float u = 1.f / (1.f + expf(-(gib[H_DIMC + j] + ghb[H_DIMC + j])));
        const float n = tanhf(gib[2 * H_DIMC + j] + r * ghb[2 * H_DIMC + j]);
        const float v = (1.f - u) * n + u * h[i];
        hn[i] = v; hnb[i] = f2bf(v);
        return;
    }
    bid -= (B_DIM * H_DIMC) / 256;
    const int KB = (B_DIM * Z_DIMC) / 256;
    float v; int target;
    if (bid < KB) {
        const int i = bid * 256 + tid;
        const float dmn = em[i] - pm[i];
        v = 0.5f * (2.f * logf(ps[i] + EPSF) - 2.f * logf(es[i] + EPSF) +
                    (es[i] * es[i] + dmn * dmn) / (ps[i] * ps[i]) - 1.f);
        target = 0;
    } else {
        const int i = (bid - KB) * 256 + tid;
        const float d = ds[i];
        const float diff = xt[i] - dm[i];
        v = logf(d + EPSF) + HALF_LOG_2PI + diff * diff / (2.f * d * d);
        target = 1;
    }
    for (int o = 32; o > 0; o >>= 1) v += __shfl_down(v, o);
    __shared__ float sred[4];
    if ((tid & 63) == 0) sred[tid >> 6] = v;
    __syncthreads();
    if (tid == 0) atomicAdd(outp + target, sred[0] + sred[1] + sred[2] + sred[3]);
}

static inline Seg seg(int n_end, const float* bias, int act, float* of32, int ld32,
                      short* ob16, int ld16)
{
    Seg s; s.n_end = n_end; s.bias = bias; s.act = act;
    s.of32 = of32; s.ld32 = ld32; s.ob16 = ob16; s.ld16 = ld16; return s;
}
static inline Seg segend() { return seg(INT_MAX, nullptr, 0, nullptr, 0, nullptr, 0); }

extern "C" void kernel_launch(void* const* d_in, const int* in_sizes, int n_in,
                              void* d_out_v, int out_size, void* d_ws, size_t ws_size,
                              hipStream_t stream)
{
    (void)in_sizes; (void)n_in; (void)out_size;
    const float* x    = (const float*)d_in[0];
    const float* h0   = (const float*)d_in[1];
    const float* eps  = (const float*)d_in[2];
    const float* Wpx  = (const float*)d_in[3];
    const float* bpx  = (const float*)d_in[4];
    const float* Wpz  = (const float*)d_in[5];
    const float* bpz  = (const float*)d_in[6];
    const float* Wenc = (const float*)d_in[7];
    const float* benc = (const float*)d_in[8];
    const float* Wem  = (const float*)d_in[9];
    const float* bem  = (const float*)d_in[10];
    const float* Wes  = (const float*)d_in[11];
    const float* bes  = (const float*)d_in[12];
    const float* Wpr  = (const float*)d_in[13];
    const float* bpr  = (const float*)d_in[14];
    const float* Wpm  = (const float*)d_in[15];
    const float* bpm  = (const float*)d_in[16];
    const float* Wps  = (const float*)d_in[17];
    const float* bps  = (const float*)d_in[18];
    const float* Wdec = (const float*)d_in[19];
    const float* bdec = (const float*)d_in[20];
    const float* Wdm  = (const float*)d_in[21];
    const float* bdm  = (const float*)d_in[22];
    const float* Wds  = (const float*)d_in[23];
    const float* bds  = (const float*)d_in[24];
    const float* W_ih = (const float*)d_in[25];
    const float* W_hh = (const float*)d_in[26];
    const float* b_ih = (const float*)d_in[27];
    const float* b_hh = (const float*)d_in[28];

    float* out = (float*)d_out_v;
    float* kld_nll   = out;
    float* enc_means = out + 2;
    float* enc_stds  = enc_means + (size_t)T_DIM * B_DIM * Z_DIMC;
    float* dec_means = enc_stds  + (size_t)T_DIM * B_DIM * Z_DIMC;
    float* dec_stds  = dec_means + (size_t)T_DIM * B_DIM * X_DIMC;

    char* wsb = (char*)d_ws;
    size_t off = 0;
    auto takeB = [&](size_t bytes) {
        char* p = wsb + off; off += (bytes + 255) & ~(size_t)255; return p;
    };
    short* WTpx = (short*)takeB((size_t)1024 * 256 * 2);
    short* WT1  = (short*)takeB((size_t)5120 * 2048 * 2);
    short* WT2  = (short*)takeB((size_t)256 * 1024 * 2);
    short* WTpz = (short*)takeB((size_t)1024 * 128 * 2);
    short* WT4  = (short*)takeB((size_t)4096 * 3072 * 2);
    short* WT56 = (short*)takeB((size_t)768 * 2048 * 2);
    short* xb   = (short*)takeB((size_t)T_DIM * B_DIM * X_DIMC * 2);
    float* hf0  = (float*)takeB((size_t)B_DIM * H_DIMC * 4);
    float* hf1  = (float*)takeB((size_t)B_DIM * H_DIMC * 4);
    short* hb0  = (short*)takeB((size_t)B_DIM * H_DIMC * 2);
    short* hb1  = (short*)takeB((size_t)B_DIM * H_DIMC * 2);
    short* enc_b   = (short*)takeB((size_t)B_DIM * H_DIMC * 2);
    short* prior_b = (short*)takeB((size_t)B_DIM * H_DIMC * 2);
    short* phi_zb  = (short*)takeB((size_t)B_DIM * H_DIMC * 2);
    short* dec_b   = (short*)takeB((size_t)B_DIM * H_DIMC * 2);
    float* ghb_ = (float*)takeB((size_t)B_DIM * 3 * H_DIMC * 4);
    float* gib_ = (float*)takeB((size_t)B_DIM * 3 * H_DIMC * 4);
    float* pmb  = (float*)takeB((size_t)B_DIM * Z_DIMC * 4);
    float* psb  = (float*)takeB((size_t)B_DIM * Z_DIMC * 4);
    const size_t phiXb_bytes = (size_t)T_DIM * B_DIM * H_DIMC * 2;
    const bool big = (off + phiXb_bytes) <= ws_size;
    short* phiXb = big ? (short*)takeB(phiXb_bytes) : nullptr;
    short* phiXs = big ? nullptr : (short*)takeB((size_t)B_DIM * H_DIMC * 2);

    const int BIG = 1 << 30;
    const dim3 tb(256), pt(32, 8);

    // ---- prologue: pack weights to bf16 B^T fused layouts ----
    // WTpx [1024][256]
    packT_k<<<dim3(32, 8), pt, 0, stream>>>(Wpx, 1024, WTpx, 256, 0, 0);
    // WT1 [5120][2048] = [enc | prior | gh]
    packT_k<<<dim3(32, 64), pt, 0, stream>>>(Wenc, 1024, WT1, 2048, 0, 0);
    packZ_k<<<dim3(1024 * 1024 / 256), tb, 0, stream>>>(WT1, 2048, 1024, 0, 1024);
    packT_k<<<dim3(32, 32), pt, 0, stream>>>(Wpr, 1024, WT1, 2048, 1024, 1024);
    packZ_k<<<dim3(3072 * 1024 / 256), tb, 0, stream>>>(WT1, 2048, 2048, 0, 1024);
    packD_k<<<dim3(3072 * 1024 / 256), tb, 0, stream>>>(W_hh, 1024, WT1, 2048, 2048, 1024, 1024);
    // WT2 [256][1024] = [em | es]
    packT_k<<<dim3(4, 32), pt, 0, stream>>>(Wem, 128, WT2, 1024, 0, 0);
    packT_k<<<dim3(4, 32), pt, 0, stream>>>(Wes, 128, WT2, 1024, 128, 0);
    // WTpz [1024][128]
    packT_k<<<dim3(32, 4), pt, 0, stream>>>(Wpz, 1024, WTpz, 128, 0, 0);
    // WT4 [4096][3072] over K=[phiX|phi_z|h] = [dec | gi]
    packZ_k<<<dim3(1024 * 1024 / 256), tb, 0, stream>>>(WT4, 3072, 0, 0, 1024);
    packT_k<<<dim3(32, 64), pt, 0, stream>>>(Wdec, 1024, WT4, 3072, 0, 1024);
    packD_k<<<dim3(3072 * 2048 / 256), tb, 0, stream>>>(W_ih, 2048, WT4, 3072, 1024, 0, 2048);
    packZ_k<<<dim3(3072 * 1024 / 256), tb, 0, stream>>>(WT4, 3072, 1024, 2048, 1024);
    // WT56 [768][2048] over K=[prior|dec] = [pm | ps | dm | ds]
    packT_k<<<dim3(4, 32), pt, 0, stream>>>(Wpm, 128, WT56, 2048, 0, 0);
    packT_k<<<dim3(4, 32), pt, 0, stream>>>(Wps, 128, WT56, 2048, 128, 0);
    packZ_k<<<dim3(256 * 1024 / 256), tb, 0, stream>>>(WT56, 2048, 0, 1024, 1024);
    packZ_k<<<dim3(512 * 1024 / 256), tb, 0, stream>>>(WT56, 2048, 256, 0, 1024);
    packT_k<<<dim3(8, 32), pt, 0, stream>>>(Wdm, 256, WT56, 2048, 256, 1024);
    packT_k<<<dim3(8, 32), pt, 0, stream>>>(Wds, 256, WT56, 2048, 512, 1024);

    cvtx_k<<<dim3((size_t)T_DIM * B_DIM * X_DIMC / 4 / 256), tb, 0, stream>>>(x, xb);
    hinit_k<<<dim3(B_DIM * H_DIMC / 256), tb, 0, stream>>>(h0, hf0, hb0);
    zero2_k<<<1, 64, 0, stream>>>(kld_nll);

    Segs sx; sx.s[0] = seg(1024, bpx, 1, nullptr, 0, phiXb ? phiXb : phiXs, 1024);
    sx.s[1] = segend(); sx.s[2] = segend(); sx.s[3] = segend();
    if (big) {
        mm_k<64, 128, 0><<<dim3(T_DIM * B_DIM / 64, 8), tb, 0, stream>>>(
            xb, 256, nullptr, 0, nullptr, 0, BIG, BIG,
            nullptr, nullptr, nullptr, 0, WTpx, 256, sx, 256);
    }

    for (int t = 0; t < T_DIM; ++t) {
        float* hcur = (t & 1) ? hf1 : hf0;
        float* hnxt = (t & 1) ? hf0 : hf1;
        short* hbc  = (t & 1) ? hb1 : hb0;
        short* hbn  = (t & 1) ? hb0 : hb1;
        const short* phiXt = big ? (phiXb + (size_t)t * B_DIM * H_DIMC) : phiXs;
        float* em_t = enc_means + (size_t)t * B_DIM * Z_DIMC;
        float* es_t = enc_stds  + (size_t)t * B_DIM * Z_DIMC;
        float* dm_t = dec_means + (size_t)t * B_DIM * X_DIMC;
        float* ds_t = dec_stds  + (size_t)t * B_DIM * X_DIMC;
        const float* eps_t = eps + (size_t)t * B_DIM * Z_DIMC;
        const float* x_t   = x   + (size_t)t * B_DIM * X_DIMC;

        if (!big) {
            mm_k<64, 128, 0><<<dim3(4, 8), tb, 0, stream>>>(
                xb + (size_t)t * B_DIM * X_DIMC, 256, nullptr, 0, nullptr, 0, BIG, BIG,
                nullptr, nullptr, nullptr, 0, WTpx, 256, sx, 256);
        }
        // G1: [phiX|h] -> enc(relu,b16) | prior(relu,b16) | gh(f32)
        Segs g1;
        g1.s[0] = seg(1024, benc, 1, nullptr, 0, enc_b, 1024);
        g1.s[1] = seg(2048, bpr, 1, nullptr, 0, prior_b, 1024);
        g1.s[2] = seg(5120, b_hh, 0, ghb_, 3 * H_DIMC, nullptr, 0);
        g1.s[3] = segend();
        mm_k<64, 128, 0><<<dim3(4, 40), tb, 0, stream>>>(
            phiXt, 1024, hbc, 1024, nullptr, 0, 1024, 2048,
            nullptr, nullptr, nullptr, 0, WT1, 2048, g1, 2048);
        // G2: enc -> em(f32) | es(softplus,f32), direct to d_out
        Segs g2;
        g2.s[0] = seg(128, bem, 0, em_t, 128, nullptr, 0);
        g2.s[1] = seg(256, bes, 2, es_t, 128, nullptr, 0);
        g2.s[2] = segend(); g2.s[3] = segend();
        mm_k<64, 64, 0><<<dim3(4, 4), tb, 0, stream>>>(
            enc_b, 1024, nullptr, 0, nullptr, 0, BIG, BIG,
            nullptr, nullptr, nullptr, 0, WT2, 1024, g2, 1024);
        // G3: z = em + eps*es (ZMODE) -> phi_z(relu,b16)
        Segs g3;
        g3.s[0] = seg(1024, bpz, 1, nullptr, 0, phi_zb, 1024);
        g3.s[1] = segend(); g3.s[2] = segend(); g3.s[3] = segend();
        mm_k<64, 128, 1><<<dim3(4, 8), tb, 0, stream>>>(
            nullptr, 0, nullptr, 0, nullptr, 0, BIG, BIG,
            em_t, es_t, eps_t, 128, WTpz, 128, g3, 128);
        // G4: [phiX|phi_z|h] -> dec(relu,b16) | gi(f32)
        Segs g4;
        g4.s[0] = seg(1024, bdec, 1, nullptr, 0, dec_b, 1024);
        g4.s[1] = seg(4096, b_ih, 0, gib_, 3 * H_DIMC, nullptr, 0);
        g4.s[2] = segend(); g4.s[3] = segend();
        mm_k<64, 128, 0><<<dim3(4, 32), tb, 0, stream>>>(
            phiXt, 1024, phi_zb, 1024, hbc, 1024, 1024, 2048,
            nullptr, nullptr, nullptr, 0, WT4, 3072, g4, 3072);
        // G56: [prior|dec] -> pm | ps(sp) | dm | ds(sp)
        Segs g5;
        g5.s[0] = seg(128, bpm, 0, pmb, 128, nullptr, 0);
        g5.s[1] = seg(256, bps, 2, psb, 128, nullptr, 0);
        g5.s[2] = seg(512, bdm, 0, dm_t, 256, nullptr, 0);
        g5.s[3] = seg(768, bds, 2, ds_t, 256, nullptr, 0);
        mm_k<64, 64, 0><<<dim3(4, 12), tb, 0, stream>>>(
            prior_b, 1024, dec_b, 1024, nullptr, 0, 1024, BIG,
            nullptr, nullptr, nullptr, 0, WT56, 2048, g5, 2048);
        // tail: GRU combine + kld/nll reduction
        tail_k<<<dim3(1408), tb, 0, stream>>>(
            gib_, ghb_, hcur, hnxt, hbn,
            em_t, es_t, pmb, psb, x_t, dm_t, ds_t, kld_nll);
    }
}

// Round 3
// 16355.046 us; speedup vs baseline: 11.1137x; 1.9761x over previous
//
#include <hip/hip_runtime.h>
#include <math.h>
#include <limits.h>

#define T_DIM 128
#define B_DIM 256
#define X_DIMC 256
#define H_DIMC 1024
#define Z_DIMC 128
#define EPSF 1.1920929e-07f
#define HALF_LOG_2PI 0.91893853320467274f

typedef float f32x4 __attribute__((ext_vector_type(4)));
typedef short bf16x8 __attribute__((ext_vector_type(8)));

// column segment: [prev n_end, n_end) uses K-range [kbeg,kend) of the virtual A
struct Seg { int n_end; int kbeg; int kend; const float* bias; int act;
             float* of32; int ld32; short* ob16; int ld16; };
struct Segs { Seg s[4]; };

__device__ __forceinline__ short f2bf(float f) {
    unsigned u = __builtin_bit_cast(unsigned, f);
    u += 0x7fffu + ((u >> 16) & 1u);
    return (short)(u >> 16);
}
__device__ __forceinline__ float act_apply(float x, int act) {
    if (act == 1) return fmaxf(x, 0.f);
    if (act == 2) return x > 0.f ? x + log1pf(expf(-x)) : log1pf(expf(x));
    return x;
}
__device__ __forceinline__ void gload16(const short* g, short* l) {
    __builtin_amdgcn_global_load_lds(
        (const __attribute__((address_space(1))) void*)g,
        (__attribute__((address_space(3))) void*)l, 16, 0, 0);
}

// Pipelined bf16 MFMA GEMM: 64x64 tile, BK=32, 4 waves (2x2 of 32x32).
// A virtual [M,K]: k<ks1 -> A0, k<ks2 -> A1, else A2 (fuses concat along K).
// B: BT [N][K] bf16 (pre-transposed, fused blocks; zero regions never read
// because each column segment iterates only its own [kbeg,kend)).
// Double-buffered global_load_lds staging with counted vmcnt (loads for tile
// i+1 stay in flight across the barrier while tile i computes).
__global__ __launch_bounds__(256) void mmp_k(
    const short* __restrict__ A0, int lda0,
    const short* __restrict__ A1, int lda1,
    const short* __restrict__ A2, int lda2,
    int ks1, int ks2,
    const short* __restrict__ BT, int ldb,
    Segs segs)
{
    __shared__ short As[2][64][32];
    __shared__ short Bs[2][64][32];
    const int tid = threadIdx.x, lane = tid & 63, wid = tid >> 6;
    const int bm0 = blockIdx.x * 64, bn0 = blockIdx.y * 64;
    int si = 0, n0 = 0;
    while (bn0 >= segs.s[si].n_end) { n0 = segs.s[si].n_end; ++si; }
    const Seg sg = segs.s[si];
    const int nit = (sg.kend - sg.kbeg) >> 5;

    // staging: each wave moves one 1KB A-chunk + one 1KB B-chunk per tile
    // (16 rows x 32 cols bf16); lane l -> row chunkbase + l/4, col (l%4)*8.
    const int arow = (wid << 4) + (lane >> 2);
    const int ac8 = (lane & 3) << 3;
    const short* A0r = A0 + (size_t)(bm0 + arow) * lda0;
    const short* A1r = A1 + (size_t)(bm0 + arow) * lda1;
    const short* A2r = A2 + (size_t)(bm0 + arow) * lda2;
    const short* Br  = BT + (size_t)(bn0 + arow) * ldb;

    auto stage = [&](int p, int it) {
        const int gk = sg.kbeg + (it << 5) + ac8;
        const short* ga = (gk < ks1) ? (A0r + gk)
                        : (gk < ks2) ? (A1r + (gk - ks1))
                                     : (A2r + (gk - ks2));
        gload16(ga, &As[p][wid << 4][0]);
        gload16(Br + gk, &Bs[p][wid << 4][0]);
    };

    const int l15 = lane & 15, lg = lane >> 4;
    const int wm = (wid >> 1) << 5, wn = (wid & 1) << 5;
    f32x4 acc[2][2] = {};

    stage(0, 0);
    for (int it = 0; it < nit; ++it) {
        const int p = it & 1;
        if (it + 1 < nit) {
            stage(p ^ 1, it + 1);
            asm volatile("s_waitcnt vmcnt(2)" ::: "memory");  // tile it landed
        } else {
            asm volatile("s_waitcnt vmcnt(0)" ::: "memory");
        }
        asm volatile("s_barrier" ::: "memory");
        bf16x8 af0 = *(const bf16x8*)&As[p][wm + l15][lg << 3];
        bf16x8 af1 = *(const bf16x8*)&As[p][wm + 16 + l15][lg << 3];
        bf16x8 bg0 = *(const bf16x8*)&Bs[p][wn + l15][lg << 3];
        bf16x8 bg1 = *(const bf16x8*)&Bs[p][wn + 16 + l15][lg << 3];
        acc[0][0] = __builtin_amdgcn_mfma_f32_16x16x32_bf16(af0, bg0, acc[0][0], 0, 0, 0);
        acc[0][1] = __builtin_amdgcn_mfma_f32_16x16x32_bf16(af0, bg1, acc[0][1], 0, 0, 0);
        acc[1][0] = __builtin_amdgcn_mfma_f32_16x16x32_bf16(af1, bg0, acc[1][0], 0, 0, 0);
        acc[1][1] = __builtin_amdgcn_mfma_f32_16x16x32_bf16(af1, bg1, acc[1][1], 0, 0, 0);
        asm volatile("s_barrier" ::: "memory");  // reads done before overwrite
    }

    // C/D mapping: col = lane&15, row = (lane>>4)*4 + r (verified r1/r2)
#pragma unroll
    for (int j = 0; j < 2; ++j) {
        const int gn = bn0 + wn + (j << 4) + l15;
        const int cn = gn - n0;
        const float bv = sg.bias[cn];
#pragma unroll
        for (int i = 0; i < 2; ++i) {
            const int gm0 = bm0 + wm + (i << 4) + (lg << 2);
#pragma unroll
            for (int r = 0; r < 4; ++r) {
                float v = act_apply(acc[i][j][r] + bv, sg.act);
                if (sg.of32) sg.of32[(size_t)(gm0 + r) * sg.ld32 + cn] = v;
                if (sg.ob16) sg.ob16[(size_t)(gm0 + r) * sg.ld16 + cn] = f2bf(v);
            }
        }
    }
}

// z-GEMM: A = em + eps*es computed on the fly (fp32 reads), K=128 fixed,
// whole K staged once (no pipeline needed: 4 MFMA slices). 64x64 tile.
__global__ __launch_bounds__(256) void zmm_k(
    const float* __restrict__ zm, const float* __restrict__ zs,
    const float* __restrict__ ze,
    const short* __restrict__ BT,  // [1024][128]
    const float* __restrict__ bias, short* __restrict__ outb)
{
    __shared__ short As[64][136];
    __shared__ short Bs[64][136];
    const int tid = threadIdx.x, lane = tid & 63, wid = tid >> 6;
    const int bm0 = blockIdx.x * 64, bn0 = blockIdx.y * 64;
    const int r = tid >> 2, c0 = (tid & 3) << 3;
#pragma unroll
    for (int s = 0; s < 4; ++s) {
        const int col = c0 + s * 32;
        const size_t base = (size_t)(bm0 + r) * 128 + col;
        short tmp[8];
#pragma unroll
        for (int q = 0; q < 8; q += 2) {
            float2 m2 = *(const float2*)(zm + base + q);
            float2 s2 = *(const float2*)(zs + base + q);
            float2 e2 = *(const float2*)(ze + base + q);
            tmp[q]     = f2bf(fmaf(e2.x, s2.x, m2.x));
            tmp[q + 1] = f2bf(fmaf(e2.y, s2.y, m2.y));
        }
        *(bf16x8*)&As[r][col] = *(bf16x8*)tmp;
        *(bf16x8*)&Bs[r][col] = *(const bf16x8*)(BT + (size_t)(bn0 + r) * 128 + col);
    }
    __syncthreads();
    const int l15 = lane & 15, lg = lane >> 4;
    const int wm = (wid >> 1) << 5, wn = (wid & 1) << 5;
    f32x4 acc[2][2] = {};
#pragma unroll
    for (int s = 0; s < 4; ++s) {
        bf16x8 af0 = *(const bf16x8*)&As[wm + l15][(lg << 3) + s * 32];
        bf16x8 af1 = *(const bf16x8*)&As[wm + 16 + l15][(lg << 3) + s * 32];
        bf16x8 bg0 = *(const bf16x8*)&Bs[wn + l15][(lg << 3) + s * 32];
        bf16x8 bg1 = *(const bf16x8*)&Bs[wn + 16 + l15][(lg << 3) + s * 32];
        acc[0][0] = __builtin_amdgcn_mfma_f32_16x16x32_bf16(af0, bg0, acc[0][0], 0, 0, 0);
        acc[0][1] = __builtin_amdgcn_mfma_f32_16x16x32_bf16(af0, bg1, acc[0][1], 0, 0, 0);
        acc[1][0] = __builtin_amdgcn_mfma_f32_16x16x32_bf16(af1, bg0, acc[1][0], 0, 0, 0);
        acc[1][1] = __builtin_amdgcn_mfma_f32_16x16x32_bf16(af1, bg1, acc[1][1], 0, 0, 0);
    }
#pragma unroll
    for (int j = 0; j < 2; ++j) {
        const int gn = bn0 + wn + (j << 4) + l15;
        const float bv = bias[gn];
#pragma unroll
        for (int i = 0; i < 2; ++i) {
            const int gm0 = bm0 + wm + (i << 4) + (lg << 2);
#pragma unroll
            for (int rr = 0; rr < 4; ++rr) {
                float v = fmaxf(acc[i][j][rr] + bv, 0.f);
                outb[(size_t)(gm0 + rr) * 1024 + gn] = f2bf(v);
            }
        }
    }
}

// dst[n0+n][k0+k] (bf16, ld ldd) = src[k][n]  (fp32, ld ldsr), LDS transpose
__global__ void packT_k(const float* __restrict__ src, int ldsr,
                        short* __restrict__ dst, int ldd, int n0, int k0)
{
    __shared__ float tile[32][33];
    const int bx = blockIdx.x * 32;  // n
    const int by = blockIdx.y * 32;  // k
    const int tx = threadIdx.x, ty = threadIdx.y;  // (32,8)
    for (int i = ty; i < 32; i += 8)
        tile[i][tx] = src[(size_t)(by + i) * ldsr + bx + tx];
    __syncthreads();
    for (int i = ty; i < 32; i += 8)
        dst[(size_t)(n0 + bx + i) * ldd + k0 + by + tx] = f2bf(tile[tx][i]);
}

// dst[n0+n][k0+k] = src[n][k] (for W_ih/W_hh which are [N][K] already)
__global__ void packD_k(const float* __restrict__ src, int ldsr,
                        short* __restrict__ dst, int ldd, int n0, int k0, int kr)
{
    const int idx = blockIdx.x * 256 + threadIdx.x;
    const int n = idx / kr, k = idx % kr;
    dst[(size_t)(n0 + n) * ldd + k0 + k] = f2bf(src[(size_t)n * ldsr + k]);
}

__global__ void cvtx_k(const float* __restrict__ x, short* __restrict__ xb)
{
    const int i = blockIdx.x * 256 + threadIdx.x;
    float4 v = ((const float4*)x)[i];
    short4 s;
    s.x = f2bf(v.x); s.y = f2bf(v.y); s.z = f2bf(v.z); s.w = f2bf(v.w);
    ((short4*)xb)[i] = s;
}

__global__ void hinit_k(const float* __restrict__ h0, float* __restrict__ hf,
                        short* __restrict__ hb)
{
    const int i = blockIdx.x * 256 + threadIdx.x;
    const float v = h0[i];
    hf[i] = v; hb[i] = f2bf(v);
}

__global__ void zero2_k(float* p) { if (threadIdx.x < 2) p[threadIdx.x] = 0.f; }

// blocks [0,1024): GRU combine; [1024,1152): kld; [1152,1408): nll
__global__ void tail_k(const float* __restrict__ gi, const float* __restrict__ gh,
                       const float* __restrict__ h, float* __restrict__ hn,
                       short* __restrict__ hnb,
                       const float* __restrict__ em, const float* __restrict__ es,
                       const float* __restrict__ pm, const float* __restrict__ ps,
                       const float* __restrict__ xt, const float* __restrict__ dm,
                       const float* __restrict__ ds, float* __restrict__ outp)
{
    int bid = blockIdx.x;
    const int tid = threadIdx.x;
    if (bid < (B_DIM * H_DIMC) / 256) {
        const int i = bid * 256 + tid;
        const int b = i >> 10, j = i & (H_DIMC - 1);
        const float* gib = gi + (size_t)b * 3 * H_DIMC;
        const float* ghb = gh + (size_t)b * 3 * H_DIMC;
        const float r = 1.f / (1.f + expf(-(gib[j] + ghb[j])));
        const float u = 1.f / (1.f + expf(-(gib[H_DIMC + j] + ghb[H_DIMC + j])));
        const float n = tanhf(gib[2 * H_DIMC + j] + r * ghb[2 * H_DIMC + j]);
        const float v = (1.f - u) * n + u * h[i];
        hn[i] = v; hnb[i] = f2bf(v);
        return;
    }
    bid -= (B_DIM * H_DIMC) / 256;
    const int KB = (B_DIM * Z_DIMC) / 256;
    float v; int target;
    if (bid < KB) {
        const int i = bid * 256 + tid;
        const float dmn = em[i] - pm[i];
        v = 0.5f * (2.f * logf(ps[i] + EPSF) - 2.f * logf(es[i] + EPSF) +
                    (es[i] * es[i] + dmn * dmn) / (ps[i] * ps[i]) - 1.f);
        target = 0;
    } else {
        const int i = (bid - KB) * 256 + tid;
        const float d = ds[i];
        const float diff = xt[i] - dm[i];
        v = logf(d + EPSF) + HALF_LOG_2PI + diff * diff / (2.f * d * d);
        target = 1;
    }
    for (int o = 32; o > 0; o >>= 1) v += __shfl_down(v, o);
    __shared__ float sred[4];
    if ((tid & 63) == 0) sred[tid >> 6] = v;
    __syncthreads();
    if (tid == 0) atomicAdd(outp + target, sred[0] + sred[1] + sred[2] + sred[3]);
}

static inline Seg seg(int n_end, int kbeg, int kend, const float* bias, int act,
                      float* of32, int ld32, short* ob16, int ld16)
{
    Seg s; s.n_end = n_end; s.kbeg = kbeg; s.kend = kend; s.bias = bias;
    s.act = act; s.of32 = of32; s.ld32 = ld32; s.ob16 = ob16; s.ld16 = ld16;
    return s;
}
static inline Seg segend() { return seg(INT_MAX, 0, 32, nullptr, 0, nullptr, 0, nullptr, 0); }

extern "C" void kernel_launch(void* const* d_in, const int* in_sizes, int n_in,
                              void* d_out_v, int out_size, void* d_ws, size_t ws_size,
                              hipStream_t stream)
{
    (void)in_sizes; (void)n_in; (void)out_size;
    const float* x    = (const float*)d_in[0];
    const float* h0   = (const float*)d_in[1];
    const float* eps  = (const float*)d_in[2];
    const float* Wpx  = (const float*)d_in[3];
    const float* bpx  = (const float*)d_in[4];
    const float* Wpz  = (const float*)d_in[5];
    const float* bpz  = (const float*)d_in[6];
    const float* Wenc = (const float*)d_in[7];
    const float* benc = (const float*)d_in[8];
    const float* Wem  = (const float*)d_in[9];
    const float* bem  = (const float*)d_in[10];
    const float* Wes  = (const float*)d_in[11];
    const float* bes  = (const float*)d_in[12];
    const float* Wpr  = (const float*)d_in[13];
    const float* bpr  = (const float*)d_in[14];
    const float* Wpm  = (const float*)d_in[15];
    const float* bpm  = (const float*)d_in[16];
    const float* Wps  = (const float*)d_in[17];
    const float* bps  = (const float*)d_in[18];
    const float* Wdec = (const float*)d_in[19];
    const float* bdec = (const float*)d_in[20];
    const float* Wdm  = (const float*)d_in[21];
    const float* bdm  = (const float*)d_in[22];
    const float* Wds  = (const float*)d_in[23];
    const float* bds  = (const float*)d_in[24];
    const float* W_ih = (const float*)d_in[25];
    const float* W_hh = (const float*)d_in[26];
    const float* b_ih = (const float*)d_in[27];
    const float* b_hh = (const float*)d_in[28];

    float* out = (float*)d_out_v;
    float* kld_nll   = out;
    float* enc_means = out + 2;
    float* enc_stds  = enc_means + (size_t)T_DIM * B_DIM * Z_DIMC;
    float* dec_means = enc_stds  + (size_t)T_DIM * B_DIM * Z_DIMC;
    float* dec_stds  = dec_means + (size_t)T_DIM * B_DIM * X_DIMC;

    char* wsb = (char*)d_ws;
    size_t off = 0;
    auto takeB = [&](size_t bytes) {
        char* p = wsb + off; off += (bytes + 255) & ~(size_t)255; return p;
    };
    short* WTpx = (short*)takeB((size_t)1024 * 256 * 2);
    short* WT1  = (short*)takeB((size_t)5120 * 2048 * 2);
    short* WT2  = (short*)takeB((size_t)256 * 1024 * 2);
    short* WTpz = (short*)takeB((size_t)1024 * 128 * 2);
    short* WT4  = (short*)takeB((size_t)4096 * 3072 * 2);
    short* WT56 = (short*)takeB((size_t)768 * 2048 * 2);
    short* xb   = (short*)takeB((size_t)T_DIM * B_DIM * X_DIMC * 2);
    float* hf0  = (float*)takeB((size_t)B_DIM * H_DIMC * 4);
    float* hf1  = (float*)takeB((size_t)B_DIM * H_DIMC * 4);
    short* hb0  = (short*)takeB((size_t)B_DIM * H_DIMC * 2);
    short* hb1  = (short*)takeB((size_t)B_DIM * H_DIMC * 2);
    short* enc_b   = (short*)takeB((size_t)B_DIM * H_DIMC * 2);
    short* prior_b = (short*)takeB((size_t)B_DIM * H_DIMC * 2);
    short* phi_zb  = (short*)takeB((size_t)B_DIM * H_DIMC * 2);
    short* dec_b   = (short*)takeB((size_t)B_DIM * H_DIMC * 2);
    float* ghb_ = (float*)takeB((size_t)B_DIM * 3 * H_DIMC * 4);
    float* gib_ = (float*)takeB((size_t)B_DIM * 3 * H_DIMC * 4);
    float* pmb  = (float*)takeB((size_t)B_DIM * Z_DIMC * 4);
    float* psb  = (float*)takeB((size_t)B_DIM * Z_DIMC * 4);
    const size_t phiXb_bytes = (size_t)T_DIM * B_DIM * H_DIMC * 2;
    const bool big = (off + phiXb_bytes) <= ws_size;
    short* phiXb = big ? (short*)takeB(phiXb_bytes) : nullptr;
    short* phiXs = big ? nullptr : (short*)takeB((size_t)B_DIM * H_DIMC * 2);

    const int BIG = 1 << 30;
    const dim3 tb(256), pt(32, 8);

    // ---- prologue: pack weights to bf16 B^T fused layouts (no zero-fill
    // needed: per-segment K-ranges never read the padding regions) ----
    packT_k<<<dim3(32, 8), pt, 0, stream>>>(Wpx, 1024, WTpx, 256, 0, 0);
    // WT1 [5120][2048], virtual K = [phiX(0:1024) | h(1024:2048)]
    packT_k<<<dim3(32, 64), pt, 0, stream>>>(Wenc, 1024, WT1, 2048, 0, 0);
    packT_k<<<dim3(32, 32), pt, 0, stream>>>(Wpr, 1024, WT1, 2048, 1024, 1024);
    packD_k<<<dim3(3072 * 1024 / 256), tb, 0, stream>>>(W_hh, 1024, WT1, 2048, 2048, 1024, 1024);
    // WT2 [256][1024] = [em | es]
    packT_k<<<dim3(4, 32), pt, 0, stream>>>(Wem, 128, WT2, 1024, 0, 0);
    packT_k<<<dim3(4, 32), pt, 0, stream>>>(Wes, 128, WT2, 1024, 128, 0);
    // WTpz [1024][128]
    packT_k<<<dim3(32, 4), pt, 0, stream>>>(Wpz, 1024, WTpz, 128, 0, 0);
    // WT4 [4096][3072], virtual K = [phiX(0:1024) | phi_z(1024:2048) | h(2048:3072)]
    packT_k<<<dim3(32, 64), pt, 0, stream>>>(Wdec, 1024, WT4, 3072, 0, 1024);
    packD_k<<<dim3(3072 * 2048 / 256), tb, 0, stream>>>(W_ih, 2048, WT4, 3072, 1024, 0, 2048);
    // WT56 [768][2048], virtual K = [prior(0:1024) | dec(1024:2048)]
    packT_k<<<dim3(4, 32), pt, 0, stream>>>(Wpm, 128, WT56, 2048, 0, 0);
    packT_k<<<dim3(4, 32), pt, 0, stream>>>(Wps, 128, WT56, 2048, 128, 0);
    packT_k<<<dim3(8, 32), pt, 0, stream>>>(Wdm, 256, WT56, 2048, 256, 1024);
    packT_k<<<dim3(8, 32), pt, 0, stream>>>(Wds, 256, WT56, 2048, 512, 1024);

    cvtx_k<<<dim3((size_t)T_DIM * B_DIM * X_DIMC / 4 / 256), tb, 0, stream>>>(x, xb);
    hinit_k<<<dim3(B_DIM * H_DIMC / 256), tb, 0, stream>>>(h0, hf0, hb0);
    zero2_k<<<1, 64, 0, stream>>>(kld_nll);

    Segs sx;
    sx.s[0] = seg(1024, 0, 256, bpx, 1, nullptr, 0, phiXb ? phiXb : phiXs, 1024);
    sx.s[1] = segend(); sx.s[2] = segend(); sx.s[3] = segend();
    if (big) {
        mm: ;
        mmp_k<<<dim3(T_DIM * B_DIM / 64, 16), tb, 0, stream>>>(
            xb, 256, xb, 256, xb, 256, BIG, BIG, WTpx, 256, sx);
    }

    for (int t = 0; t < T_DIM; ++t) {
        float* hcur = (t & 1) ? hf1 : hf0;
        float* hnxt = (t & 1) ? hf0 : hf1;
        short* hbc  = (t & 1) ? hb1 : hb0;
        short* hbn  = (t & 1) ? hb0 : hb1;
        const short* phiXt = big ? (phiXb + (size_t)t * B_DIM * H_DIMC) : phiXs;
        float* em_t = enc_means + (size_t)t * B_DIM * Z_DIMC;
        float* es_t = enc_stds  + (size_t)t * B_DIM * Z_DIMC;
        float* dm_t = dec_means + (size_t)t * B_DIM * X_DIMC;
        float* ds_t = dec_stds  + (size_t)t * B_DIM * X_DIMC;
        const float* eps_t = eps + (size_t)t * B_DIM * Z_DIMC;
        const float* x_t   = x   + (size_t)t * B_DIM * X_DIMC;

        if (!big) {
            mmp_k<<<dim3(4, 16), tb, 0, stream>>>(
                xb + (size_t)t * B_DIM * X_DIMC, 256,
                xb, 256, xb, 256, BIG, BIG, WTpx, 256, sx);
        }
        // G1: [phiX|h] -> enc(relu,K 0:2048) | prior(relu,K 1024:2048) | gh(K 1024:2048)
        Segs g1;
        g1.s[0] = seg(1024, 0, 2048, benc, 1, nullptr, 0, enc_b, 1024);
        g1.s[1] = seg(2048, 1024, 2048, bpr, 1, nullptr, 0, prior_b, 1024);
        g1.s[2] = seg(5120, 1024, 2048, b_hh, 0, ghb_, 3 * H_DIMC, nullptr, 0);
        g1.s[3] = segend();
        mmp_k<<<dim3(4, 80), tb, 0, stream>>>(
            phiXt, 1024, hbc, 1024, hbc, 1024, 1024, BIG, WT1, 2048, g1);
        // G2: enc -> em | es(softplus), direct to d_out
        Segs g2;
        g2.s[0] = seg(128, 0, 1024, bem, 0, em_t, 128, nullptr, 0);
        g2.s[1] = seg(256, 0, 1024, bes, 2, es_t, 128, nullptr, 0);
        g2.s[2] = segend(); g2.s[3] = segend();
        mmp_k<<<dim3(4, 4), tb, 0, stream>>>(
            enc_b, 1024, enc_b, 1024, enc_b, 1024, BIG, BIG, WT2, 1024, g2);
        // G3: z = em + eps*es -> phi_z(relu)
        zmm_k<<<dim3(4, 16), tb, 0, stream>>>(em_t, es_t, eps_t, WTpz, bpz, phi_zb);
        // G4: [phiX|phi_z|h] -> dec(relu, K 1024:3072) | gi(K 0:2048)
        Segs g4;
        g4.s[0] = seg(1024, 1024, 3072, bdec, 1, nullptr, 0, dec_b, 1024);
        g4.s[1] = seg(4096, 0, 2048, b_ih, 0, gib_, 3 * H_DIMC, nullptr, 0);
        g4.s[2] = segend(); g4.s[3] = segend();
        mmp_k<<<dim3(4, 64), tb, 0, stream>>>(
            phiXt, 1024, phi_zb, 1024, hbc, 1024, 1024, 2048, WT4, 3072, g4);
        // G56: [prior|dec] -> pm | ps(sp) | dm | ds(sp)
        Segs g5;
        g5.s[0] = seg(128, 0, 1024, bpm, 0, pmb, 128, nullptr, 0);
        g5.s[1] = seg(256, 0, 1024, bps, 2, psb, 128, nullptr, 0);
        g5.s[2] = seg(512, 1024, 2048, bdm, 0, dm_t, 256, nullptr, 0);
        g5.s[3] = seg(768, 1024, 2048, bds, 2, ds_t, 256, nullptr, 0);
        mmp_k<<<dim3(4, 12), tb, 0, stream>>>(
            prior_b, 1024, dec_b, 1024, dec_b, 1024, 1024, BIG, WT56, 2048, g5);
        // tail: GRU combine + kld/nll reduction
        tail_k<<<dim3(1408), tb, 0, stream>>>(
            gib_, ghb_, hcur, hnxt, hbn,
            em_t, es_t, pmb, psb, x_t, dm_t, ds_t, kld_nll);
    }
}

// Round 4
// 14038.629 us; speedup vs baseline: 12.9474x; 1.1650x over previous
//
#include <hip/hip_runtime.h>
#include <math.h>
#include <limits.h>

#define T_DIM 128
#define B_DIM 256
#define X_DIMC 256
#define H_DIMC 1024
#define Z_DIMC 128
#define EPSF 1.1920929e-07f
#define HALF_LOG_2PI 0.91893853320467274f

typedef float f32x4 __attribute__((ext_vector_type(4)));
typedef short bf16x8 __attribute__((ext_vector_type(8)));

// column segment: [prev n_end, n_end) uses K-range [kbeg,kend) of the virtual A
struct Seg { int n_end; int kbeg; int kend; const float* bias; int act;
             float* of32; int ld32; short* ob16; int ld16; };
struct Segs { Seg s[4]; };

// extra-work payload piggybacked on GEMM launches (blockIdx.y >= nby)
struct Extra {
    const float* gi; const float* gh; const float* h; float* hn; short* hnb;
    const float* em; const float* es; const float* pm; const float* ps;
    const float* xt; const float* dm; const float* ds; float* outp;
    int nby; int enable;
};

__device__ __forceinline__ short f2bf(float f) {
    unsigned u = __builtin_bit_cast(unsigned, f);
    u += 0x7fffu + ((u >> 16) & 1u);
    return (short)(u >> 16);
}
__device__ __forceinline__ float act_apply(float x, int act) {
    if (act == 1) return fmaxf(x, 0.f);
    if (act == 2) return x > 0.f ? x + log1pf(expf(-x)) : log1pf(expf(x));
    return x;
}
__device__ __forceinline__ void gload16(const short* g, short* l) {
    __builtin_amdgcn_global_load_lds(
        (const __attribute__((address_space(1))) void*)g,
        (__attribute__((address_space(3))) void*)l, 16, 0, 0);
}

__device__ __forceinline__ void gru_body(int bid, int tid, const Extra& ex) {
    const int i = bid * 256 + tid;
    const int b = i >> 10, j = i & (H_DIMC - 1);
    const float* gib = ex.gi + (size_t)b * 3 * H_DIMC;
    const float* ghb = ex.gh + (size_t)b * 3 * H_DIMC;
    const float r = 1.f / (1.f + expf(-(gib[j] + ghb[j])));
    const float u = 1.f / (1.f + expf(-(gib[H_DIMC + j] + ghb[H_DIMC + j])));
    const float n = tanhf(gib[2 * H_DIMC + j] + r * ghb[2 * H_DIMC + j]);
    const float v = (1.f - u) * n + u * ex.h[i];
    ex.hn[i] = v; ex.hnb[i] = f2bf(v);
}

// bid in [0,384): [0,128) kld over B*Z, [128,384) nll over B*X
__device__ __forceinline__ void loss_body(int bid, int tid, const Extra& ex,
                                          float* sred) {
    const int KB = (B_DIM * Z_DIMC) / 256;  // 128
    float v; int target;
    if (bid < KB) {
        const int i = bid * 256 + tid;
        const float dmn = ex.em[i] - ex.pm[i];
        v = 0.5f * (2.f * logf(ex.ps[i] + EPSF) - 2.f * logf(ex.es[i] + EPSF) +
                    (ex.es[i] * ex.es[i] + dmn * dmn) / (ex.ps[i] * ex.ps[i]) - 1.f);
        target = 0;
    } else {
        const int i = (bid - KB) * 256 + tid;
        const float d = ex.ds[i];
        const float diff = ex.xt[i] - ex.dm[i];
        v = logf(d + EPSF) + HALF_LOG_2PI + diff * diff / (2.f * d * d);
        target = 1;
    }
    for (int o = 32; o > 0; o >>= 1) v += __shfl_down(v, o);
    if ((tid & 63) == 0) sred[tid >> 6] = v;
    __syncthreads();
    if (tid == 0) atomicAdd(ex.outp + target, sred[0] + sred[1] + sred[2] + sred[3]);
}

// Deep-pipelined bf16 MFMA GEMM: 64x64 tile, BK=64, depth-3 prefetch with
// counted vmcnt (2 tiles of loads stay in flight across barriers).
// A virtual [M,K]: k<ks1 -> A0, k<ks2 -> A1, else A2 (fuses concat along K).
// B: BT [N][K] bf16 pre-transposed. LDS is written linearly by
// global_load_lds; bank conflicts on ds_read_b128 are avoided by
// pre-swizzling the GLOBAL source column (col8 ^= row&7) and applying the
// same XOR on the read side (both-sides involution, rule #21).
// EXTRA: 0 none, 1 GRU blocks (by>=nby), 2 loss blocks (by>=nby).
template <int EXTRA>
__global__ __launch_bounds__(256) void mmp_k(
    const short* __restrict__ A0, int lda0,
    const short* __restrict__ A1, int lda1,
    const short* __restrict__ A2, int lda2,
    int ks1, int ks2,
    const short* __restrict__ BT, int ldb,
    Segs segs, Extra ex)
{
    __shared__ short As[3][64][64];
    __shared__ short Bs[3][64][64];
    __shared__ float sred[4];
    const int tid = threadIdx.x, lane = tid & 63, wid = tid >> 6;
    if (EXTRA) {
        const int by = blockIdx.y;
        if (by >= ex.nby) {
            const int bid = (by - ex.nby) * 4 + blockIdx.x;
            if (EXTRA == 1) gru_body(bid, tid, ex);
            else if (ex.enable) loss_body(bid, tid, ex, sred);
            return;
        }
    }
    const int bm0 = blockIdx.x * 64, bn0 = blockIdx.y * 64;
    int si = 0, n0 = 0;
    while (bn0 >= segs.s[si].n_end) { n0 = segs.s[si].n_end; ++si; }
    const Seg sg = segs.s[si];
    const int nit = (sg.kend - sg.kbeg) >> 6;

    // staging geometry: wave w moves A rows [16w,16w+16) and B rows same,
    // as 2 chunks of 8 rows x 64 cols (1KB = 64 lanes x 16B each).
    // lane l -> row chunkbase + l/8, source col8 = (l%8) ^ (l/8)  (swizzle).
    const int row8 = lane >> 3;
    const int kc = (((lane & 7) ^ row8) << 3);  // source k-offset in shorts
    const int r0 = (wid << 4) + row8, r1 = r0 + 8;

    auto stage = [&](int p, int it) {
        const int gk = sg.kbeg + (it << 6) + kc;
        const short* ga0 = (gk < ks1) ? A0 + (size_t)(bm0 + r0) * lda0 + gk
                         : (gk < ks2) ? A1 + (size_t)(bm0 + r0) * lda1 + (gk - ks1)
                                      : A2 + (size_t)(bm0 + r0) * lda2 + (gk - ks2);
        const short* ga1 = (gk < ks1) ? A0 + (size_t)(bm0 + r1) * lda0 + gk
                         : (gk < ks2) ? A1 + (size_t)(bm0 + r1) * lda1 + (gk - ks1)
                                      : A2 + (size_t)(bm0 + r1) * lda2 + (gk - ks2);
        gload16(ga0, &As[p][(wid << 4) + 0][0]);
        gload16(ga1, &As[p][(wid << 4) + 8][0]);
        gload16(BT + (size_t)(bn0 + r0) * ldb + gk, &Bs[p][(wid << 4) + 0][0]);
        gload16(BT + (size_t)(bn0 + r1) * ldb + gk, &Bs[p][(wid << 4) + 8][0]);
    };

    const int l15 = lane & 15, lg = lane >> 4;
    const int wm = (wid >> 1) << 5, wn = (wid & 1) << 5;
    const int swz = (l15 & 7) << 3;
    const int c0 = (lg << 3) ^ swz;          // k-slice 0 read col (shorts)
    const int c1 = (32 + (lg << 3)) ^ swz;   // k-slice 1 read col
    f32x4 acc[2][2] = {};

    stage(0, 0);
    if (nit > 1) stage(1, 1);
    if (nit > 2) stage(2, 2);
    int p = 0;
    for (int it = 0; it < nit; ++it) {
        const int rem = nit - 1 - it;
        if (rem >= 2)      asm volatile("s_waitcnt vmcnt(8)" ::: "memory");
        else if (rem == 1) asm volatile("s_waitcnt vmcnt(4)" ::: "memory");
        else               asm volatile("s_waitcnt vmcnt(0)" ::: "memory");
        asm volatile("s_barrier" ::: "memory");
        bf16x8 a00 = *(const bf16x8*)&As[p][wm + l15][c0];
        bf16x8 a01 = *(const bf16x8*)&As[p][wm + l15][c1];
        bf16x8 a10 = *(const bf16x8*)&As[p][wm + 16 + l15][c0];
        bf16x8 a11 = *(const bf16x8*)&As[p][wm + 16 + l15][c1];
        bf16x8 b00 = *(const bf16x8*)&Bs[p][wn + l15][c0];
        bf16x8 b01 = *(const bf16x8*)&Bs[p][wn + l15][c1];
        bf16x8 b10 = *(const bf16x8*)&Bs[p][wn + 16 + l15][c0];
        bf16x8 b11 = *(const bf16x8*)&Bs[p][wn + 16 + l15][c1];
        acc[0][0] = __builtin_amdgcn_mfma_f32_16x16x32_bf16(a00, b00, acc[0][0], 0, 0, 0);
        acc[0][1] = __builtin_amdgcn_mfma_f32_16x16x32_bf16(a00, b10, acc[0][1], 0, 0, 0);
        acc[1][0] = __builtin_amdgcn_mfma_f32_16x16x32_bf16(a10, b00, acc[1][0], 0, 0, 0);
        acc[1][1] = __builtin_amdgcn_mfma_f32_16x16x32_bf16(a10, b10, acc[1][1], 0, 0, 0);
        acc[0][0] = __builtin_amdgcn_mfma_f32_16x16x32_bf16(a01, b01, acc[0][0], 0, 0, 0);
        acc[0][1] = __builtin_amdgcn_mfma_f32_16x16x32_bf16(a01, b11, acc[0][1], 0, 0, 0);
        acc[1][0] = __builtin_amdgcn_mfma_f32_16x16x32_bf16(a11, b01, acc[1][0], 0, 0, 0);
        acc[1][1] = __builtin_amdgcn_mfma_f32_16x16x32_bf16(a11, b11, acc[1][1], 0, 0, 0);
        if (rem >= 3) {
            // all waves done reading buf p before restaging into it
            asm volatile("s_waitcnt lgkmcnt(0)\n\ts_barrier" ::: "memory");
            stage(p, it + 3);
        }
        p = (p == 2) ? 0 : p + 1;
    }

    // C/D mapping: col = lane&15, row = (lane>>4)*4 + r
#pragma unroll
    for (int j = 0; j < 2; ++j) {
        const int gn = bn0 + wn + (j << 4) + l15;
        const int cn = gn - n0;
        const float bv = sg.bias[cn];
#pragma unroll
        for (int i = 0; i < 2; ++i) {
            const int gm0 = bm0 + wm + (i << 4) + (lg << 2);
#pragma unroll
            for (int r = 0; r < 4; ++r) {
                float v = act_apply(acc[i][j][r] + bv, sg.act);
                if (sg.of32) sg.of32[(size_t)(gm0 + r) * sg.ld32 + cn] = v;
                if (sg.ob16) sg.ob16[(size_t)(gm0 + r) * sg.ld16 + cn] = f2bf(v);
            }
        }
    }
}

// z-GEMM: A = em + eps*es computed on the fly (fp32 reads), K=128, one-shot
// LDS staging (VALU path, padded layout -> conflict-free). 64x64 tile.
__global__ __launch_bounds__(256) void zmm_k(
    const float* __restrict__ zm, const float* __restrict__ zs,
    const float* __restrict__ ze,
    const short* __restrict__ BT,  // [1024][128]
    const float* __restrict__ bias, short* __restrict__ outb)
{
    __shared__ short As[64][136];
    __shared__ short Bs[64][136];
    const int tid = threadIdx.x, lane = tid & 63, wid = tid >> 6;
    const int bm0 = blockIdx.x * 64, bn0 = blockIdx.y * 64;
    const int r = tid >> 2, c0 = (tid & 3) << 3;
#pragma unroll
    for (int s = 0; s < 4; ++s) {
        const int col = c0 + s * 32;
        const size_t base = (size_t)(bm0 + r) * 128 + col;
        short tmp[8];
#pragma unroll
        for (int q = 0; q < 8; q += 2) {
            float2 m2 = *(const float2*)(zm + base + q);
            float2 s2 = *(const float2*)(zs + base + q);
            float2 e2 = *(const float2*)(ze + base + q);
            tmp[q]     = f2bf(fmaf(e2.x, s2.x, m2.x));
            tmp[q + 1] = f2bf(fmaf(e2.y, s2.y, m2.y));
        }
        *(bf16x8*)&As[r][col] = *(bf16x8*)tmp;
        *(bf16x8*)&Bs[r][col] = *(const bf16x8*)(BT + (size_t)(bn0 + r) * 128 + col);
    }
    __syncthreads();
    const int l15 = lane & 15, lg = lane >> 4;
    const int wm = (wid >> 1) << 5, wn = (wid & 1) << 5;
    f32x4 acc[2][2] = {};
#pragma unroll
    for (int s = 0; s < 4; ++s) {
        bf16x8 af0 = *(const bf16x8*)&As[wm + l15][(lg << 3) + s * 32];
        bf16x8 af1 = *(const bf16x8*)&As[wm + 16 + l15][(lg << 3) + s * 32];
        bf16x8 bg0 = *(const bf16x8*)&Bs[wn + l15][(lg << 3) + s * 32];
        bf16x8 bg1 = *(const bf16x8*)&Bs[wn + 16 + l15][(lg << 3) + s * 32];
        acc[0][0] = __builtin_amdgcn_mfma_f32_16x16x32_bf16(af0, bg0, acc[0][0], 0, 0, 0);
        acc[0][1] = __builtin_amdgcn_mfma_f32_16x16x32_bf16(af0, bg1, acc[0][1], 0, 0, 0);
        acc[1][0] = __builtin_amdgcn_mfma_f32_16x16x32_bf16(af1, bg0, acc[1][0], 0, 0, 0);
        acc[1][1] = __builtin_amdgcn_mfma_f32_16x16x32_bf16(af1, bg1, acc[1][1], 0, 0, 0);
    }
#pragma unroll
    for (int j = 0; j < 2; ++j) {
        const int gn = bn0 + wn + (j << 4) + l15;
        const float bv = bias[gn];
#pragma unroll
        for (int i = 0; i < 2; ++i) {
            const int gm0 = bm0 + wm + (i << 4) + (lg << 2);
#pragma unroll
            for (int rr = 0; rr < 4; ++rr) {
                float v = fmaxf(acc[i][j][rr] + bv, 0.f);
                outb[(size_t)(gm0 + rr) * 1024 + gn] = f2bf(v);
            }
        }
    }
}

// dst[n0+n][k0+k] (bf16, ld ldd) = src[k][n]  (fp32, ld ldsr), LDS transpose
__global__ void packT_k(const float* __restrict__ src, int ldsr,
                        short* __restrict__ dst, int ldd, int n0, int k0)
{
    __shared__ float tile[32][33];
    const int bx = blockIdx.x * 32;  // n
    const int by = blockIdx.y * 32;  // k
    const int tx = threadIdx.x, ty = threadIdx.y;  // (32,8)
    for (int i = ty; i < 32; i += 8)
        tile[i][tx] = src[(size_t)(by + i) * ldsr + bx + tx];
    __syncthreads();
    for (int i = ty; i < 32; i += 8)
        dst[(size_t)(n0 + bx + i) * ldd + k0 + by + tx] = f2bf(tile[tx][i]);
}

// dst[n0+n][k0+k] = src[n][k] (for W_ih/W_hh which are [N][K] already)
__global__ void packD_k(const float* __restrict__ src, int ldsr,
                        short* __restrict__ dst, int ldd, int n0, int k0, int kr)
{
    const int idx = blockIdx.x * 256 + threadIdx.x;
    const int n = idx / kr, k = idx % kr;
    dst[(size_t)(n0 + n) * ldd + k0 + k] = f2bf(src[(size_t)n * ldsr + k]);
}

__global__ void cvtx_k(const float* __restrict__ x, short* __restrict__ xb)
{
    const int i = blockIdx.x * 256 + threadIdx.x;
    float4 v = ((const float4*)x)[i];
    short4 s;
    s.x = f2bf(v.x); s.y = f2bf(v.y); s.z = f2bf(v.z); s.w = f2bf(v.w);
    ((short4*)xb)[i] = s;
}

__global__ void hinit_k(const float* __restrict__ h0, float* __restrict__ hf,
                        short* __restrict__ hb)
{
    const int i = blockIdx.x * 256 + threadIdx.x;
    const float v = h0[i];
    hf[i] = v; hb[i] = f2bf(v);
}

__global__ void zero2_k(float* p) { if (threadIdx.x < 2) p[threadIdx.x] = 0.f; }

__global__ void fin_k(Extra ex)
{
    __shared__ float sred[4];
    loss_body(blockIdx.x, threadIdx.x, ex, sred);
}

static inline Seg seg(int n_end, int kbeg, int kend, const float* bias, int act,
                      float* of32, int ld32, short* ob16, int ld16)
{
    Seg s; s.n_end = n_end; s.kbeg = kbeg; s.kend = kend; s.bias = bias;
    s.act = act; s.of32 = of32; s.ld32 = ld32; s.ob16 = ob16; s.ld16 = ld16;
    return s;
}
static inline Seg segend() { return seg(INT_MAX, 0, 64, nullptr, 0, nullptr, 0, nullptr, 0); }

extern "C" void kernel_launch(void* const* d_in, const int* in_sizes, int n_in,
                              void* d_out_v, int out_size, void* d_ws, size_t ws_size,
                              hipStream_t stream)
{
    (void)in_sizes; (void)n_in; (void)out_size;
    const float* x    = (const float*)d_in[0];
    const float* h0   = (const float*)d_in[1];
    const float* eps  = (const float*)d_in[2];
    const float* Wpx  = (const float*)d_in[3];
    const float* bpx  = (const float*)d_in[4];
    const float* Wpz  = (const float*)d_in[5];
    const float* bpz  = (const float*)d_in[6];
    const float* Wenc = (const float*)d_in[7];
    const float* benc = (const float*)d_in[8];
    const float* Wem  = (const float*)d_in[9];
    const float* bem  = (const float*)d_in[10];
    const float* Wes  = (const float*)d_in[11];
    const float* bes  = (const float*)d_in[12];
    const float* Wpr  = (const float*)d_in[13];
    const float* bpr  = (const float*)d_in[14];
    const float* Wpm  = (const float*)d_in[15];
    const float* bpm  = (const float*)d_in[16];
    const float* Wps  = (const float*)d_in[17];
    const float* bps  = (const float*)d_in[18];
    const float* Wdec = (const float*)d_in[19];
    const float* bdec = (const float*)d_in[20];
    const float* Wdm  = (const float*)d_in[21];
    const float* bdm  = (const float*)d_in[22];
    const float* Wds  = (const float*)d_in[23];
    const float* bds  = (const float*)d_in[24];
    const float* W_ih = (const float*)d_in[25];
    const float* W_hh = (const float*)d_in[26];
    const float* b_ih = (const float*)d_in[27];
    const float* b_hh = (const float*)d_in[28];

    float* out = (float*)d_out_v;
    float* kld_nll   = out;
    float* enc_means = out + 2;
    float* enc_stds  = enc_means + (size_t)T_DIM * B_DIM * Z_DIMC;
    float* dec_means = enc_stds  + (size_t)T_DIM * B_DIM * Z_DIMC;
    float* dec_stds  = dec_means + (size_t)T_DIM * B_DIM * X_DIMC;

    char* wsb = (char*)d_ws;
    size_t off = 0;
    auto takeB = [&](size_t bytes) {
        char* p = wsb + off; off += (bytes + 255) & ~(size_t)255; return p;
    };
    short* WTpx = (short*)takeB((size_t)1024 * 256 * 2);
    short* WT1  = (short*)takeB((size_t)5120 * 2048 * 2);
    short* WT2  = (short*)takeB((size_t)256 * 1024 * 2);
    short* WTpz = (short*)takeB((size_t)1024 * 128 * 2);
    short* WT4  = (short*)takeB((size_t)4096 * 3072 * 2);
    short* WT56 = (short*)takeB((size_t)768 * 2048 * 2);
    short* xb   = (short*)takeB((size_t)T_DIM * B_DIM * X_DIMC * 2);
    float* hf0  = (float*)takeB((size_t)B_DIM * H_DIMC * 4);
    float* hf1  = (float*)takeB((size_t)B_DIM * H_DIMC * 4);
    short* hb0  = (short*)takeB((size_t)B_DIM * H_DIMC * 2);
    short* hb1  = (short*)takeB((size_t)B_DIM * H_DIMC * 2);
    short* enc_b   = (short*)takeB((size_t)B_DIM * H_DIMC * 2);
    short* prior_b = (short*)takeB((size_t)B_DIM * H_DIMC * 2);
    short* phi_zb  = (short*)takeB((size_t)B_DIM * H_DIMC * 2);
    short* dec_b   = (short*)takeB((size_t)B_DIM * H_DIMC * 2);
    float* ghb_ = (float*)takeB((size_t)B_DIM * 3 * H_DIMC * 4);
    float* gib_ = (float*)takeB((size_t)B_DIM * 3 * H_DIMC * 4);
    float* pmb  = (float*)takeB((size_t)B_DIM * Z_DIMC * 4);
    float* psb  = (float*)takeB((size_t)B_DIM * Z_DIMC * 4);
    const size_t phiXb_bytes = (size_t)T_DIM * B_DIM * H_DIMC * 2;
    const bool big = (off + phiXb_bytes) <= ws_size;
    short* phiXb = big ? (short*)takeB(phiXb_bytes) : nullptr;
    short* phiXs = big ? nullptr : (short*)takeB((size_t)B_DIM * H_DIMC * 2);

    const int BIG = 1 << 30;
    const dim3 tb(256), pt(32, 8);

    Extra exnone = {};
    exnone.nby = INT_MAX;

    // ---- prologue: pack weights to bf16 B^T fused layouts ----
    packT_k<<<dim3(32, 8), pt, 0, stream>>>(Wpx, 1024, WTpx, 256, 0, 0);
    // WT1 [5120][2048], virtual K = [phiX(0:1024) | h(1024:2048)]
    packT_k<<<dim3(32, 64), pt, 0, stream>>>(Wenc, 1024, WT1, 2048, 0, 0);
    packT_k<<<dim3(32, 32), pt, 0, stream>>>(Wpr, 1024, WT1, 2048, 1024, 1024);
    packD_k<<<dim3(3072 * 1024 / 256), tb, 0, stream>>>(W_hh, 1024, WT1, 2048, 2048, 1024, 1024);
    // WT2 [256][1024] = [em | es]
    packT_k<<<dim3(4, 32), pt, 0, stream>>>(Wem, 128, WT2, 1024, 0, 0);
    packT_k<<<dim3(4, 32), pt, 0, stream>>>(Wes, 128, WT2, 1024, 128, 0);
    // WTpz [1024][128]
    packT_k<<<dim3(32, 4), pt, 0, stream>>>(Wpz, 1024, WTpz, 128, 0, 0);
    // WT4 [4096][3072], virtual K = [phiX(0:1024) | phi_z(1024:2048) | h(2048:3072)]
    packT_k<<<dim3(32, 64), pt, 0, stream>>>(Wdec, 1024, WT4, 3072, 0, 1024);
    packD_k<<<dim3(3072 * 2048 / 256), tb, 0, stream>>>(W_ih, 2048, WT4, 3072, 1024, 0, 2048);
    // WT56 [768][2048], virtual K = [prior(0:1024) | dec(1024:2048)]
    packT_k<<<dim3(4, 32), pt, 0, stream>>>(Wpm, 128, WT56, 2048, 0, 0);
    packT_k<<<dim3(4, 32), pt, 0, stream>>>(Wps, 128, WT56, 2048, 128, 0);
    packT_k<<<dim3(8, 32), pt, 0, stream>>>(Wdm, 256, WT56, 2048, 256, 1024);
    packT_k<<<dim3(8, 32), pt, 0, stream>>>(Wds, 256, WT56, 2048, 512, 1024);

    cvtx_k<<<dim3((size_t)T_DIM * B_DIM * X_DIMC / 4 / 256), tb, 0, stream>>>(x, xb);
    hinit_k<<<dim3(B_DIM * H_DIMC / 256), tb, 0, stream>>>(h0, hf0, hb0);
    zero2_k<<<1, 64, 0, stream>>>(kld_nll);

    Segs sx;
    sx.s[0] = seg(1024, 0, 256, bpx, 1, nullptr, 0, phiXb ? phiXb : phiXs, 1024);
    sx.s[1] = segend(); sx.s[2] = segend(); sx.s[3] = segend();
    if (big) {
        mmp_k<0><<<dim3(T_DIM * B_DIM / 64, 16), tb, 0, stream>>>(
            xb, 256, xb, 256, xb, 256, BIG, BIG, WTpx, 256, sx, exnone);
    }

    for (int t = 0; t < T_DIM; ++t) {
        float* hcur = (t & 1) ? hf1 : hf0;
        float* hnxt = (t & 1) ? hf0 : hf1;
        short* hbc  = (t & 1) ? hb1 : hb0;
        short* hbn  = (t & 1) ? hb0 : hb1;
        const short* phiXt = big ? (phiXb + (size_t)t * B_DIM * H_DIMC) : phiXs;
        float* em_t = enc_means + (size_t)t * B_DIM * Z_DIMC;
        float* es_t = enc_stds  + (size_t)t * B_DIM * Z_DIMC;
        float* dm_t = dec_means + (size_t)t * B_DIM * X_DIMC;
        float* ds_t = dec_stds  + (size_t)t * B_DIM * X_DIMC;
        const float* eps_t = eps + (size_t)t * B_DIM * Z_DIMC;
        const float* x_t   = x   + (size_t)t * B_DIM * X_DIMC;

        if (!big) {
            mmp_k<0><<<dim3(4, 16), tb, 0, stream>>>(
                xb + (size_t)t * B_DIM * X_DIMC, 256,
                xb, 256, xb, 256, BIG, BIG, WTpx, 256, sx, exnone);
        }
        // G1: [phiX|h] -> enc | prior | gh, plus loss(t-1) blocks (by>=80)
        Segs g1;
        g1.s[0] = seg(1024, 0, 2048, benc, 1, nullptr, 0, enc_b, 1024);
        g1.s[1] = seg(2048, 1024, 2048, bpr, 1, nullptr, 0, prior_b, 1024);
        g1.s[2] = seg(5120, 1024, 2048, b_hh, 0, ghb_, 3 * H_DIMC, nullptr, 0);
        g1.s[3] = segend();
        {
            const int tp = (t > 0) ? t - 1 : 0;
            Extra exl = {};
            exl.em = enc_means + (size_t)tp * B_DIM * Z_DIMC;
            exl.es = enc_stds  + (size_t)tp * B_DIM * Z_DIMC;
            exl.pm = pmb; exl.ps = psb;
            exl.xt = x + (size_t)tp * B_DIM * X_DIMC;
            exl.dm = dec_means + (size_t)tp * B_DIM * X_DIMC;
            exl.ds = dec_stds  + (size_t)tp * B_DIM * X_DIMC;
            exl.outp = kld_nll; exl.nby = 80; exl.enable = (t > 0);
            mmp_k<2><<<dim3(4, 176), tb, 0, stream>>>(
                phiXt, 1024, hbc, 1024, hbc, 1024, 1024, BIG, WT1, 2048, g1, exl);
        }
        // G2: enc -> em | es(softplus), direct to d_out
        Segs g2;
        g2.s[0] = seg(128, 0, 1024, bem, 0, em_t, 128, nullptr, 0);
        g2.s[1] = seg(256, 0, 1024, bes, 2, es_t, 128, nullptr, 0);
        g2.s[2] = segend(); g2.s[3] = segend();
        mmp_k<0><<<dim3(4, 4), tb, 0, stream>>>(
            enc_b, 1024, enc_b, 1024, enc_b, 1024, BIG, BIG, WT2, 1024, g2, exnone);
        // G3: z = em + eps*es -> phi_z(relu)
        zmm_k<<<dim3(4, 16), tb, 0, stream>>>(em_t, es_t, eps_t, WTpz, bpz, phi_zb);
        // G4: [phiX|phi_z|h] -> dec(relu, K 1024:3072) | gi(K 0:2048)
        Segs g4;
        g4.s[0] = seg(1024, 1024, 3072, bdec, 1, nullptr, 0, dec_b, 1024);
        g4.s[1] = seg(4096, 0, 2048, b_ih, 0, gib_, 3 * H_DIMC, nullptr, 0);
        g4.s[2] = segend(); g4.s[3] = segend();
        mmp_k<0><<<dim3(4, 64), tb, 0, stream>>>(
            phiXt, 1024, phi_zb, 1024, hbc, 1024, 1024, 2048, WT4, 3072, g4, exnone);
        // G56: [prior|dec] -> pm | ps(sp) | dm | ds(sp), plus GRU blocks (by>=12)
        Segs g5;
        g5.s[0] = seg(128, 0, 1024, bpm, 0, pmb, 128, nullptr, 0);
        g5.s[1] = seg(256, 0, 1024, bps, 2, psb, 128, nullptr, 0);
        g5.s[2] = seg(512, 1024, 2048, bdm, 0, dm_t, 256, nullptr, 0);
        g5.s[3] = seg(768, 1024, 2048, bds, 2, ds_t, 256, nullptr, 0);
        {
            Extra exg = {};
            exg.gi = gib_; exg.gh = ghb_; exg.h = hcur; exg.hn = hnxt; exg.hnb = hbn;
            exg.nby = 12; exg.enable = 1;
            mmp_k<1><<<dim3(4, 268), tb, 0, stream>>>(
                prior_b, 1024, dec_b, 1024, dec_b, 1024, 1024, BIG, WT56, 2048, g5, exg);
        }
    }
    // final loss for t = T-1
    {
        const int tp = T_DIM - 1;
        Extra exf = {};
        exf.em = enc_means + (size_t)tp * B_DIM * Z_DIMC;
        exf.es = enc_stds  + (size_t)tp * B_DIM * Z_DIMC;
        exf.pm = pmb; exf.ps = psb;
        exf.xt = x + (size_t)tp * B_DIM * X_DIMC;
        exf.dm = dec_means + (size_t)tp * B_DIM * X_DIMC;
        exf.ds = dec_stds  + (size_t)tp * B_DIM * X_DIMC;
        exf.outp = kld_nll; exf.nby = 0; exf.enable = 1;
        fin_k<<<dim3(384), tb, 0, stream>>>(exf);
    }
}